// Round 1
// baseline (64.456 us; speedup 1.0000x reference)
//
#include <hip/hip_runtime.h>
#include <math.h>

constexpr int B = 16, C = 3, H = 512, W = 384, N = 18;

// ---------------- threefry2x32 (JAX-compatible, key = (0,1)) ----------------
__device__ __forceinline__ unsigned rotl32(unsigned x, int d) {
    return (x << d) | (x >> (32 - d));
}

__device__ void threefry2x32_01(unsigned c0, unsigned c1, unsigned& o0, unsigned& o1) {
    const unsigned ks0 = 0u, ks1 = 1u, ks2 = 0x1BD11BDBu;  // 0 ^ 1 ^ 0x1BD11BDA
    unsigned x0 = c0 + ks0;
    unsigned x1 = c1 + ks1;
#define R4(a,b,c,d)                               \
    x0 += x1; x1 = rotl32(x1,(a)); x1 ^= x0;      \
    x0 += x1; x1 = rotl32(x1,(b)); x1 ^= x0;      \
    x0 += x1; x1 = rotl32(x1,(c)); x1 ^= x0;      \
    x0 += x1; x1 = rotl32(x1,(d)); x1 ^= x0;
    R4(13,15,26,6)   x0 += ks1; x1 += ks2 + 1u;
    R4(17,29,16,24)  x0 += ks2; x1 += ks0 + 2u;
    R4(13,15,26,6)   x0 += ks0; x1 += ks1 + 3u;
    R4(17,29,16,24)  x0 += ks1; x1 += ks2 + 4u;
    R4(13,15,26,6)   x0 += ks2; x1 += ks0 + 5u;
#undef R4
    o0 = x0; o1 = x1;
}

// -------- per-batch: jitter, build A (f64), solve 18x18 w/ pivoting --------
// params layout per batch (72 floats): [0..35] dst interleaved (x,y),
//                                      [36..71] nodes interleaved (nx,ny)
__global__ __launch_bounds__(64) void solve_kernel(
        const float* __restrict__ keypoints,      // (B,N,2)
        const float* __restrict__ control_points, // (N,2)
        float* __restrict__ params) {
    const int b = blockIdx.x;
    const int tid = threadIdx.x;
    __shared__ float dst[2 * N];
    __shared__ double Ab[N][21];   // cols 0..17 = A, 18..19 = rhs, 20 = pad
    __shared__ double xs[2][N];
    __shared__ int piv;

    if (tid < 2 * N) {
        const int e = b * 2 * N + tid;  // global element index in (16,18,2)
        // JAX random_bits: iota(576) split in halves -> lanes (i, i+288)
        const unsigned lo = (e < 288) ? (unsigned)e : (unsigned)(e - 288);
        unsigned o0, o1;
        threefry2x32_01(lo, lo + 288u, o0, o1);
        const unsigned bits = (e < 288) ? o0 : o1;
        // uniform in [lo, 1) with lo = nextafter(-1,0)
        const float f = __uint_as_float(0x3F800000u | (bits >> 9)) - 1.0f;
        const float lof = __uint_as_float(0xBF7FFFFFu);        // -0.99999994
        const float span = __uint_as_float(0x3FFFFFFFu);       //  1.99999994
        float u = f * span + lof;
        u = fmaxf(u, lof);
        const float nrm = 1.41421356f * erfinvf(u);            // sqrt(2) f32
        dst[tid] = keypoints[e] + 1e-5f * nrm;
    }
    __syncthreads();

    // Build A in f64 from f32 dst
    for (int idx = tid; idx < N * N; idx += 64) {
        const int i = idx / N, j = idx % N;
        const double dx = (double)dst[2 * i]     - (double)dst[2 * j];
        const double dy = (double)dst[2 * i + 1] - (double)dst[2 * j + 1];
        const double d2 = dx * dx + dy * dy;
        const double phi = (d2 > 0.0) ? 0.5 * d2 * log(d2) : 0.0;
        Ab[i][j] = phi - (i == j ? 1e-5 : 0.0);
    }
    if (tid < 2 * N) {
        Ab[tid >> 1][18 + (tid & 1)] = (double)control_points[tid];
    }
    __syncthreads();

    // Gaussian elimination with partial pivoting
    for (int k = 0; k < N; ++k) {
        if (tid == 0) {
            int p = k; double best = fabs(Ab[k][k]);
            for (int i = k + 1; i < N; ++i) {
                const double v = fabs(Ab[i][k]);
                if (v > best) { best = v; p = i; }
            }
            piv = p;
        }
        __syncthreads();
        const int p = piv;
        if (p != k && tid < 20) {
            const double t = Ab[k][tid]; Ab[k][tid] = Ab[p][tid]; Ab[p][tid] = t;
        }
        __syncthreads();
        if (tid > k && tid < N) {
            const double m = Ab[tid][k] / Ab[k][k];
            for (int j = k + 1; j < 20; ++j) Ab[tid][j] -= m * Ab[k][j];
            Ab[tid][k] = 0.0;
        }
        __syncthreads();
    }
    // Back-substitution (one thread per RHS column)
    if (tid < 2) {
        for (int i = N - 1; i >= 0; --i) {
            double s = Ab[i][18 + tid];
            for (int j = i + 1; j < N; ++j) s -= Ab[i][j] * xs[tid][j];
            xs[tid][i] = s / Ab[i][i];
        }
    }
    __syncthreads();

    float* pb = params + b * 72;
    if (tid < 2 * N) pb[tid] = dst[tid];
    if (tid < 2 * N) pb[36 + tid] = (float)xs[tid & 1][tid >> 1];
}

// ---------------- per-pixel TPS evaluation + bilinear sample ----------------
__global__ __launch_bounds__(256) void warp_kernel(
        const float* __restrict__ image,   // (B,C,H,W)
        const float* __restrict__ params,  // (B,72)
        float* __restrict__ out) {         // (B,C,H,W)
    constexpr int BLOCKS_PER_BATCH = (H * W) / 256;  // 768
    const int bx = blockIdx.x;
    const int b = bx / BLOCKS_PER_BATCH;
    const int pix = (bx % BLOCKS_PER_BATCH) * 256 + threadIdx.x;
    const int y = pix / W;
    const int x = pix - y * W;

    const float* __restrict__ pb = params + b * 72;  // block-uniform -> s_load
    const float px = (float)x, py = (float)y;
    float accx = 0.f, accy = 0.f;
#pragma unroll
    for (int n = 0; n < N; ++n) {
        const float dx = px - pb[2 * n];
        const float dy = py - pb[2 * n + 1];
        const float r2 = dx * dx + dy * dy;
        const float phi = (r2 > 0.f) ? 0.5f * r2 * logf(r2) : 0.f;
        accx = fmaf(phi, pb[36 + 2 * n], accx);
        accy = fmaf(phi, pb[36 + 2 * n + 1], accy);
    }

    const float wx = fminf(fmaxf(accx, 0.f), (float)(W - 1));
    const float wy = fminf(fmaxf(accy, 0.f), (float)(H - 1));
    const float xf = floorf(wx), yf = floorf(wy);
    const int x0 = min(max((int)xf, 0), W - 1);
    const int x1 = min(max((int)(xf + 1.f), 0), W - 1);
    const int y0 = min(max((int)yf, 0), H - 1);
    const int y1 = min(max((int)(yf + 1.f), 0), H - 1);
    // weights use CLIPPED integer corners (reference semantics: exact-edge -> 0)
    const float wa = ((float)x1 - wx) * ((float)y1 - wy);
    const float wb = ((float)x1 - wx) * (wy - (float)y0);
    const float wc = (wx - (float)x0) * ((float)y1 - wy);
    const float wd = (wx - (float)x0) * (wy - (float)y0);

    const float* imb = image + (size_t)b * C * H * W;
    float* outb = out + (size_t)b * C * H * W;
#pragma unroll
    for (int c = 0; c < C; ++c) {
        const float* ch = imb + c * H * W;
        const float Ia = ch[y0 * W + x0];
        const float Ib = ch[y1 * W + x0];
        const float Ic = ch[y0 * W + x1];
        const float Id = ch[y1 * W + x1];
        outb[c * H * W + y * W + x] = wa * Ia + wb * Ib + wc * Ic + wd * Id;
    }
}

extern "C" void kernel_launch(void* const* d_in, const int* in_sizes, int n_in,
                              void* d_out, int out_size, void* d_ws, size_t ws_size,
                              hipStream_t stream) {
    const float* cloth     = (const float*)d_in[0];
    const float* keypoints = (const float*)d_in[1];
    const float* ctrl      = (const float*)d_in[2];
    float* params = (float*)d_ws;  // 16*72 floats = 4.6 KB

    solve_kernel<<<B, 64, 0, stream>>>(keypoints, ctrl, params);
    warp_kernel<<<(B * H * W) / 256, 256, 0, stream>>>(cloth, params, (float*)d_out);
}

// Round 2
// 48.241 us; speedup vs baseline: 1.3361x; 1.3361x over previous
//
#include <hip/hip_runtime.h>
#include <math.h>

constexpr int B = 16, C = 3, H = 512, W = 384, N = 18;
constexpr int HW = H * W;

using v2f = __attribute__((ext_vector_type(2))) float;

// ---------------- threefry2x32 (JAX-compatible, key = (0,1)) ----------------
__device__ __forceinline__ unsigned rotl32(unsigned x, int d) {
    return (x << d) | (x >> (32 - d));
}

__device__ void threefry2x32_01(unsigned c0, unsigned c1, unsigned& o0, unsigned& o1) {
    const unsigned ks0 = 0u, ks1 = 1u, ks2 = 0x1BD11BDBu;  // 0 ^ 1 ^ 0x1BD11BDA
    unsigned x0 = c0 + ks0;
    unsigned x1 = c1 + ks1;
#define R4(a,b,c,d)                               \
    x0 += x1; x1 = rotl32(x1,(a)); x1 ^= x0;      \
    x0 += x1; x1 = rotl32(x1,(b)); x1 ^= x0;      \
    x0 += x1; x1 = rotl32(x1,(c)); x1 ^= x0;      \
    x0 += x1; x1 = rotl32(x1,(d)); x1 ^= x0;
    R4(13,15,26,6)   x0 += ks1; x1 += ks2 + 1u;
    R4(17,29,16,24)  x0 += ks2; x1 += ks0 + 2u;
    R4(13,15,26,6)   x0 += ks0; x1 += ks1 + 3u;
    R4(17,29,16,24)  x0 += ks1; x1 += ks2 + 4u;
    R4(13,15,26,6)   x0 += ks2; x1 += ks0 + 5u;
#undef R4
    o0 = x0; o1 = x1;
}

// -------- per-batch: jitter, build A (f64), Gauss-Jordan w/ pivoting --------
// params layout per batch (72 floats, PLANAR):
//   [0..17] dst.x  [18..35] dst.y  [36..53] 0.5*ln2*nodes.x  [54..71] 0.5*ln2*nodes.y
__global__ __launch_bounds__(64) void solve_kernel(
        const float* __restrict__ keypoints,      // (B,N,2)
        const float* __restrict__ control_points, // (N,2)
        float* __restrict__ params) {
    const int b = blockIdx.x;
    const int tid = threadIdx.x;
    __shared__ float dstx[N], dsty[N];
    __shared__ double Ab[N][21];   // cols 0..17 = A, 18..19 = rhs, 20 = pad

    if (tid < 2 * N) {
        const int e = b * 2 * N + tid;  // global element index in (16,18,2)
        // JAX random_bits: iota(576) split in halves -> lanes (i, i+288)
        const unsigned lo = (e < 288) ? (unsigned)e : (unsigned)(e - 288);
        unsigned o0, o1;
        threefry2x32_01(lo, lo + 288u, o0, o1);
        const unsigned bits = (e < 288) ? o0 : o1;
        const float f = __uint_as_float(0x3F800000u | (bits >> 9)) - 1.0f;
        const float lof = __uint_as_float(0xBF7FFFFFu);        // -0.99999994
        const float span = __uint_as_float(0x3FFFFFFFu);       //  1.99999994
        float u = f * span + lof;
        u = fmaxf(u, lof);
        const float nrm = 1.41421356f * erfinvf(u);            // sqrt(2) f32
        const float v = keypoints[e] + 1e-5f * nrm;
        if ((tid & 1) == 0) dstx[tid >> 1] = v; else dsty[tid >> 1] = v;
    }
    __syncthreads();

    // Build A in f64 from f32 dst
    for (int idx = tid; idx < N * N; idx += 64) {
        const int i = idx / N, j = idx % N;
        const double dx = (double)dstx[i] - (double)dstx[j];
        const double dy = (double)dsty[i] - (double)dsty[j];
        const double d2 = dx * dx + dy * dy;
        const double phi = (d2 > 0.0) ? 0.5 * d2 * log(d2) : 0.0;
        Ab[i][j] = phi - (i == j ? 1e-5 : 0.0);
    }
    if (tid < 2 * N) {
        Ab[tid >> 1][18 + (tid & 1)] = (double)control_points[tid];
    }
    __syncthreads();

    // Gauss-Jordan with partial pivoting (no serial back-substitution)
    for (int k = 0; k < N; ++k) {
        // wave-parallel argmax over rows i >= k (rows live in lanes 0..17)
        double v = (tid >= k && tid < N) ? fabs(Ab[tid][k]) : -1.0;
        int idxl = tid;
#pragma unroll
        for (int off = 16; off >= 1; off >>= 1) {
            const double ov = __shfl_xor(v, off);
            const int oi = __shfl_xor(idxl, off);
            if (ov > v) { v = ov; idxl = oi; }
        }
        const int p = __shfl(idxl, 0);
        if (p != k && tid < 20) {
            const double t = Ab[k][tid]; Ab[k][tid] = Ab[p][tid]; Ab[p][tid] = t;
        }
        __syncthreads();
        const double inv = 1.0 / Ab[k][k];
        if (tid < N && tid != k) {
            const double m = Ab[tid][k] * inv;
#pragma unroll
            for (int j = 0; j < 20; ++j) Ab[tid][j] -= m * Ab[k][j];
        }
        __syncthreads();
    }

    float* pb = params + b * 72;
    if (tid < N) {
        pb[tid]      = dstx[tid];
        pb[18 + tid] = dsty[tid];
        // solution, with 0.5*ln2 folded in (warp kernel uses native log2)
        const double sc = 0.34657359027997264;  // 0.5 * ln(2)
        pb[36 + tid] = (float)(sc * Ab[tid][18] / Ab[tid][tid]);
        pb[54 + tid] = (float)(sc * Ab[tid][19] / Ab[tid][tid]);
    }
}

// ---------------- per-pixel TPS evaluation + bilinear sample ----------------
// 2 horizontally-adjacent pixels per thread (shared dy, packed f32 math)
__global__ __launch_bounds__(256) void warp_kernel(
        const float* __restrict__ image,   // (B,C,H,W)
        const float* __restrict__ params,  // (B,72) planar
        float* __restrict__ out) {         // (B,C,H,W)
    constexpr int PPB = 512;               // pixels per block
    constexpr int BPB = HW / PPB;          // 384 blocks per batch
    const int blk = blockIdx.x;
    const int b = blk / BPB;
    const int pix0 = (blk - b * BPB) * PPB + threadIdx.x * 2;
    const int y = pix0 / W;
    const int x = pix0 - y * W;            // even; pair (x, x+1) same row

    const float* __restrict__ pb = params + b * 72;  // block-uniform -> s_load
    const float py = (float)y;
    const v2f px = { (float)x, (float)(x + 1) };
    v2f ax = { 0.f, 0.f }, ay = { 0.f, 0.f };
#pragma unroll
    for (int n = 0; n < N; ++n) {
        const float kx = pb[n];
        const float ky = pb[18 + n];
        const float nx = pb[36 + n];       // pre-scaled by 0.5*ln2
        const float ny = pb[54 + n];
        const v2f dx = px - kx;
        const float dy = py - ky;
        const float dy2 = dy * dy;
        v2f r2 = dx * dx + dy2;
        r2.x = fmaxf(r2.x, 1e-30f);        // r2==0 -> phi ~ -1e-28 ~= 0
        r2.y = fmaxf(r2.y, 1e-30f);
        v2f lg;
        lg.x = __builtin_amdgcn_logf(r2.x);  // native v_log_f32 (log2)
        lg.y = __builtin_amdgcn_logf(r2.y);
        const v2f phi = r2 * lg;            // phi2 = r2*log2(r2); x0.5ln2 folded
        ax += phi * nx;
        ay += phi * ny;
    }

    const float* imb = image + (size_t)b * C * HW;
    float* outb = out + (size_t)b * C * HW;
    v2f o0, o1, o2;
#pragma unroll
    for (int j = 0; j < 2; ++j) {
        const float wx = fminf(fmaxf(ax[j], 0.f), (float)(W - 1));
        const float wy = fminf(fmaxf(ay[j], 0.f), (float)(H - 1));
        const float xf = floorf(wx), yf = floorf(wy);
        const int x0 = min(max((int)xf, 0), W - 1);
        const int x1 = min(max((int)(xf + 1.f), 0), W - 1);
        const int y0 = min(max((int)yf, 0), H - 1);
        const int y1 = min(max((int)(yf + 1.f), 0), H - 1);
        // weights use CLIPPED integer corners (reference semantics)
        const float wa = ((float)x1 - wx) * ((float)y1 - wy);
        const float wb = ((float)x1 - wx) * (wy - (float)y0);
        const float wc = (wx - (float)x0) * ((float)y1 - wy);
        const float wd = (wx - (float)x0) * (wy - (float)y0);
        const int ia = y0 * W + x0, ib = y1 * W + x0;
        const int ic = y0 * W + x1, id = y1 * W + x1;
        {
            const float* ch = imb;
            o0[j] = wa * ch[ia] + wb * ch[ib] + wc * ch[ic] + wd * ch[id];
        }
        {
            const float* ch = imb + HW;
            o1[j] = wa * ch[ia] + wb * ch[ib] + wc * ch[ic] + wd * ch[id];
        }
        {
            const float* ch = imb + 2 * HW;
            o2[j] = wa * ch[ia] + wb * ch[ib] + wc * ch[ic] + wd * ch[id];
        }
    }
    *reinterpret_cast<v2f*>(outb + pix0) = o0;
    *reinterpret_cast<v2f*>(outb + HW + pix0) = o1;
    *reinterpret_cast<v2f*>(outb + 2 * HW + pix0) = o2;
}

extern "C" void kernel_launch(void* const* d_in, const int* in_sizes, int n_in,
                              void* d_out, int out_size, void* d_ws, size_t ws_size,
                              hipStream_t stream) {
    const float* cloth     = (const float*)d_in[0];
    const float* keypoints = (const float*)d_in[1];
    const float* ctrl      = (const float*)d_in[2];
    float* params = (float*)d_ws;  // 16*72 floats = 4.6 KB

    solve_kernel<<<B, 64, 0, stream>>>(keypoints, ctrl, params);
    warp_kernel<<<(B * HW) / 512, 256, 0, stream>>>(cloth, params, (float*)d_out);
}

// Round 3
// 44.847 us; speedup vs baseline: 1.4373x; 1.0757x over previous
//
#include <hip/hip_runtime.h>
#include <math.h>

constexpr int B = 16, C = 3, H = 512, W = 384, N = 18;
constexpr int HW = H * W;

using v4f = __attribute__((ext_vector_type(4))) float;

// ---------------- threefry2x32 (JAX-compatible, key = (0,1)) ----------------
__device__ __forceinline__ unsigned rotl32(unsigned x, int d) {
    return (x << d) | (x >> (32 - d));
}

__device__ void threefry2x32_01(unsigned c0, unsigned c1, unsigned& o0, unsigned& o1) {
    const unsigned ks0 = 0u, ks1 = 1u, ks2 = 0x1BD11BDBu;  // 0 ^ 1 ^ 0x1BD11BDA
    unsigned x0 = c0 + ks0;
    unsigned x1 = c1 + ks1;
#define R4(a,b,c,d)                               \
    x0 += x1; x1 = rotl32(x1,(a)); x1 ^= x0;      \
    x0 += x1; x1 = rotl32(x1,(b)); x1 ^= x0;      \
    x0 += x1; x1 = rotl32(x1,(c)); x1 ^= x0;      \
    x0 += x1; x1 = rotl32(x1,(d)); x1 ^= x0;
    R4(13,15,26,6)   x0 += ks1; x1 += ks2 + 1u;
    R4(17,29,16,24)  x0 += ks2; x1 += ks0 + 2u;
    R4(13,15,26,6)   x0 += ks0; x1 += ks1 + 3u;
    R4(17,29,16,24)  x0 += ks1; x1 += ks2 + 4u;
    R4(13,15,26,6)   x0 += ks2; x1 += ks0 + 5u;
#undef R4
    o0 = x0; o1 = x1;
}

// -------- per-batch: jitter, build A (f64), register Gauss-Jordan ----------
// params layout per batch (72 floats, PLANAR):
//   [0..17] dst.x  [18..35] dst.y  [36..53] 0.5*ln2*nodes.x  [54..71] 0.5*ln2*nodes.y
__global__ __launch_bounds__(64) void solve_kernel(
        const float* __restrict__ keypoints,      // (B,N,2)
        const float* __restrict__ control_points, // (N,2)
        float* __restrict__ params) {
    const int b = blockIdx.x;
    const int tid = threadIdx.x;
    __shared__ float dstx[N], dsty[N];
    __shared__ double Ab[N][20];   // cols 0..17 = A, 18..19 = rhs

    if (tid < 2 * N) {
        const int e = b * 2 * N + tid;  // element index in (16,18,2)
        const unsigned lo = (e < 288) ? (unsigned)e : (unsigned)(e - 288);
        unsigned o0, o1;
        threefry2x32_01(lo, lo + 288u, o0, o1);
        const unsigned bits = (e < 288) ? o0 : o1;
        const float f = __uint_as_float(0x3F800000u | (bits >> 9)) - 1.0f;
        const float lof = __uint_as_float(0xBF7FFFFFu);        // -0.99999994
        const float span = __uint_as_float(0x3FFFFFFFu);       //  1.99999994
        float u = f * span + lof;
        u = fmaxf(u, lof);
        const float nrm = 1.41421356f * erfinvf(u);            // sqrt(2) f32
        const float v = keypoints[e] + 1e-5f * nrm;
        if ((tid & 1) == 0) dstx[tid >> 1] = v; else dsty[tid >> 1] = v;
    }
    __syncthreads();

    // Build [A | rhs] in f64, spread across all 64 lanes (parallel f64 logs)
    for (int idx = tid; idx < N * 20; idx += 64) {
        const int i = idx / 20, j = idx - (idx / 20) * 20;
        double v;
        if (j < N) {
            const double dx = (double)dstx[i] - (double)dstx[j];
            const double dy = (double)dsty[i] - (double)dsty[j];
            const double d2 = dx * dx + dy * dy;
            const double phi = (d2 > 0.0) ? 0.5 * d2 * log(d2) : 0.0;
            v = phi - (i == j ? 1e-5 : 0.0);
        } else {
            v = (double)control_points[2 * i + (j - N)];
        }
        Ab[i][j] = v;
    }
    __syncthreads();

    // Each lane owns one row in registers (lanes >= 18 mirror row 17, inert)
    const int row = min(tid, N - 1);
    double a[20];
#pragma unroll
    for (int j = 0; j < 20; ++j) a[j] = Ab[row][j];

    bool used = (tid >= N);
    double invs = 0.0;
    int myvar = -1;

#pragma unroll
    for (int k = 0; k < N; ++k) {
        // wave argmax of |a[k]| over unused rows (first-max tie-break)
        double cand = used ? -1.0 : fabs(a[k]);
        int il = tid;
#pragma unroll
        for (int off = 32; off >= 1; off >>= 1) {
            const double oc = __shfl_xor(cand, off);
            const int oi = __shfl_xor(il, off);
            if (oc > cand || (oc == cand && oi < il)) { cand = oc; il = oi; }
        }
        const int p = __shfl(il, 0);
        const double piv = __shfl(a[k], p);
        const double inv = 1.0 / piv;
        const bool iam = (tid == p);
        if (iam) { used = true; myvar = k; invs = inv; }
        const double m = iam ? 0.0 : a[k] * inv;
        // eliminate column k from all non-pivot rows, j in (k..17] + rhs only
        // (earlier-pivoted columns are structurally zero for every live read)
#pragma unroll
        for (int j = k + 1; j < 20; ++j) {
            const double prj = __shfl(a[j], p);
            a[j] = fma(-m, prj, a[j]);
        }
    }

    float* pb = params + b * 72;
    if (tid < N) { pb[tid] = dstx[tid]; pb[18 + tid] = dsty[tid]; }
    if (myvar >= 0) {
        const double sc = 0.34657359027997264;  // 0.5 * ln(2): warp uses log2
        pb[36 + myvar] = (float)(sc * a[18] * invs);
        pb[54 + myvar] = (float)(sc * a[19] * invs);
    }
}

// ---------------- per-pixel TPS evaluation + bilinear sample ----------------
// 4 horizontally-adjacent pixels per thread; XCD-chunked block swizzle
__global__ __launch_bounds__(256) void warp_kernel(
        const float* __restrict__ image,   // (B,C,H,W)
        const float* __restrict__ params,  // (B,72) planar
        float* __restrict__ out) {         // (B,C,H,W)
    constexpr int PPB = 1024;              // pixels per block
    constexpr int BPB = HW / PPB;          // 192 blocks per batch
    constexpr int NBLK = B * BPB;          // 3072 (divisible by 8 -> simple swz)
    const int bid = blockIdx.x;
    const int swz = (bid & 7) * (NBLK / 8) + (bid >> 3);
    const int b = swz / BPB;
    const int pix0 = (swz - b * BPB) * PPB + threadIdx.x * 4;
    const int y = pix0 / W;
    const int x = pix0 - y * W;            // W%4==0: 4 px never straddle rows

    const float* __restrict__ pb = params + b * 72;  // block-uniform -> s_load
    const float py = (float)y;
    const v4f px = { (float)x, (float)(x + 1), (float)(x + 2), (float)(x + 3) };
    v4f ax = { 0.f, 0.f, 0.f, 0.f }, ay = { 0.f, 0.f, 0.f, 0.f };
#pragma unroll
    for (int n = 0; n < N; ++n) {
        const float kx = pb[n];
        const float ky = pb[18 + n];
        const float nx = pb[36 + n];       // pre-scaled by 0.5*ln2
        const float ny = pb[54 + n];
        const float dy = py - ky;
        const float dy2 = dy * dy;
        const v4f dx = px - kx;
        v4f r2 = dx * dx + dy2;
        v4f lg;
#pragma unroll
        for (int j = 0; j < 4; ++j) {
            r2[j] = fmaxf(r2[j], 1e-30f);  // r2==0 -> phi ~ -1e-28 ~= 0
            lg[j] = __builtin_amdgcn_logf(r2[j]);  // native v_log_f32 (log2)
        }
        const v4f phi = r2 * lg;
        ax += phi * nx;
        ay += phi * ny;
    }

    const float* imb = image + (size_t)b * C * HW;
    float* outb = out + (size_t)b * C * HW;
    v4f o0, o1, o2;
#pragma unroll
    for (int j = 0; j < 4; ++j) {
        const float wx = fminf(fmaxf(ax[j], 0.f), (float)(W - 1));
        const float wy = fminf(fmaxf(ay[j], 0.f), (float)(H - 1));
        const float xf = floorf(wx), yf = floorf(wy);
        const int x0 = min(max((int)xf, 0), W - 1);
        const int x1 = min(max((int)(xf + 1.f), 0), W - 1);
        const int y0 = min(max((int)yf, 0), H - 1);
        const int y1 = min(max((int)(yf + 1.f), 0), H - 1);
        // weights use CLIPPED integer corners (reference semantics)
        const float wa = ((float)x1 - wx) * ((float)y1 - wy);
        const float wb = ((float)x1 - wx) * (wy - (float)y0);
        const float wc = (wx - (float)x0) * ((float)y1 - wy);
        const float wd = (wx - (float)x0) * (wy - (float)y0);
        const int ia = y0 * W + x0, ib = y1 * W + x0;
        const int ic = y0 * W + x1, id = y1 * W + x1;
        o0[j] = wa * imb[ia] + wb * imb[ib] + wc * imb[ic] + wd * imb[id];
        const float* c1 = imb + HW;
        o1[j] = wa * c1[ia] + wb * c1[ib] + wc * c1[ic] + wd * c1[id];
        const float* c2 = imb + 2 * HW;
        o2[j] = wa * c2[ia] + wb * c2[ib] + wc * c2[ic] + wd * c2[id];
    }
    *reinterpret_cast<v4f*>(outb + pix0) = o0;
    *reinterpret_cast<v4f*>(outb + HW + pix0) = o1;
    *reinterpret_cast<v4f*>(outb + 2 * HW + pix0) = o2;
}

extern "C" void kernel_launch(void* const* d_in, const int* in_sizes, int n_in,
                              void* d_out, int out_size, void* d_ws, size_t ws_size,
                              hipStream_t stream) {
    const float* cloth     = (const float*)d_in[0];
    const float* keypoints = (const float*)d_in[1];
    const float* ctrl      = (const float*)d_in[2];
    float* params = (float*)d_ws;  // 16*72 floats = 4.6 KB

    solve_kernel<<<B, 64, 0, stream>>>(keypoints, ctrl, params);
    warp_kernel<<<(B * HW) / 1024, 256, 0, stream>>>(cloth, params, (float*)d_out);
}